// Round 1
// baseline (248.915 us; speedup 1.0000x reference)
//
#include <hip/hip_runtime.h>

#define NB 32
#define NN 500
#define HIN 64
#define HHID 16
#define NHEAD 8
#define NVALID 400
#define MAXK 128
#define NEG_INF -1e20f

// ---------------- K0: neighbor list build (wave per row, ballot compaction) ----------------
__global__ __launch_bounds__(256) void k_nbr(const float* __restrict__ A,
                                             int* __restrict__ nbr, int* __restrict__ cnt)
{
    int row = blockIdx.x * 4 + (threadIdx.x >> 6);   // b*NN + n
    int lane = threadIdx.x & 63;
    if (row >= NB * NN) return;
    const float* arow = A + (size_t)row * NN;
    int c = 0;
    for (int it = 0; it < 8; ++it) {
        int m = it * 64 + lane;
        bool v = (m < NN) && (arow[m] > 0.0f);
        unsigned long long bal = __ballot(v);
        if (v) {
            int pos = c + __popcll(bal & ((1ull << lane) - 1ull));
            if (pos < MAXK) nbr[(size_t)row * MAXK + pos] = m;
        }
        c += (int)__popcll(bal);
    }
    if (lane == 0) cnt[row] = c < MAXK ? c : MAXK;
}

// ---------------- K1: layer-1 projection + e_src1/e_dst1 ----------------
// grid (32 chunks, NB), block 256 = 2 node-slots x (8 heads x 16 out)
__global__ __launch_bounds__(256) void k_proj1(const float* __restrict__ x, const float* __restrict__ w1,
                                               const float* __restrict__ as1, const float* __restrict__ ad1,
                                               float* __restrict__ h1p, float* __restrict__ e1s,
                                               float* __restrict__ e1d)
{
    int b = blockIdx.y, chunk = blockIdx.x;
    int t = threadIdx.x, slot = t >> 7, lane = t & 127;
    int h = lane >> 4, o = lane & 15;
    float wreg[64];
#pragma unroll
    for (int f = 0; f < 64; ++f) wreg[f] = w1[h * 1024 + f * 16 + o];
    float as_r = as1[h * 16 + o], ad_r = ad1[h * 16 + o];
    __shared__ __align__(16) float xs[2][64];
    for (int i = 0; i < 8; ++i) {
        int n = chunk * 16 + i * 2 + slot;
        bool valid = n < NN;
        if (valid && lane < 64) xs[slot][lane] = x[(size_t)(b * NN + n) * HIN + lane];
        __syncthreads();
        if (valid) {
            float acc = 0.f;
#pragma unroll
            for (int f4 = 0; f4 < 16; ++f4) {
                float4 xv = *(const float4*)&xs[slot][f4 * 4];
                acc += xv.x * wreg[f4 * 4] + xv.y * wreg[f4 * 4 + 1]
                     + xv.z * wreg[f4 * 4 + 2] + xv.w * wreg[f4 * 4 + 3];
            }
            h1p[((size_t)(b * NHEAD + h) * NN + n) * HHID + o] = acc;
            float vs = acc * as_r, vd = acc * ad_r;
#pragma unroll
            for (int m = 1; m < 16; m <<= 1) { vs += __shfl_xor(vs, m); vd += __shfl_xor(vd, m); }
            if (o == 0) {
                e1s[(size_t)(b * NHEAD + h) * NN + n] = vs;
                e1d[(size_t)(b * NHEAD + h) * NN + n] = vd;
            }
        }
        __syncthreads();
    }
}

// ---------------- K2: layer-1 sparse attention aggregate + ELU -> h1cat ----------------
__global__ __launch_bounds__(128) void k_agg1(const int* __restrict__ nbr, const int* __restrict__ cnt,
                                              const float* __restrict__ h1p, const float* __restrict__ e1s,
                                              const float* __restrict__ e1d, float* __restrict__ h1cat)
{
    int row = blockIdx.x;           // b*NN + n
    int b = row / NN, n = row - b * NN;
    int t = threadIdx.x;
    __shared__ int nb_s[MAXK];
    __shared__ float p_s[NHEAD][MAXK];
    __shared__ float stat[NHEAD][2];
    int K = cnt[row];
    for (int k = t; k < K; k += 128) nb_s[k] = nbr[(size_t)row * MAXK + k];
    __syncthreads();
    for (int idx = t; idx < NHEAD * K; idx += 128) {
        int h = idx / K, k = idx - h * K;
        float e = e1s[(size_t)(b * NHEAD + h) * NN + n]
                + e1d[(size_t)(b * NHEAD + h) * NN + nb_s[k]];
        p_s[h][k] = e > 0.f ? e : 0.2f * e;
    }
    __syncthreads();
    if (t < NHEAD) {
        float mx = -1e30f;
        for (int k = 0; k < K; ++k) mx = fmaxf(mx, p_s[t][k]);
        float sum = 0.f;
        for (int k = 0; k < K; ++k) sum += __expf(p_s[t][k] - mx);
        stat[t][0] = mx; stat[t][1] = 1.f / sum;
    }
    __syncthreads();
    for (int idx = t; idx < NHEAD * K; idx += 128) {
        int h = idx / K, k = idx - h * K;
        p_s[h][k] = __expf(p_s[h][k] - stat[h][0]) * stat[h][1];
    }
    __syncthreads();
    int h = t >> 4, o = t & 15;
    float acc = 0.f;
    const float* hp = h1p + (size_t)(b * NHEAD + h) * NN * HHID + o;
    for (int k = 0; k < K; ++k) acc += p_s[h][k] * hp[(size_t)nb_s[k] * HHID];
    float outv = acc > 0.f ? acc : expm1f(acc);     // ELU
    h1cat[(size_t)row * (NHEAD * HHID) + t] = outv;
}

// ---------------- K3: layer-2 projection + e_src2/e_dst2 ----------------
// block 256 = 2 node-slots x (2 f-halves x 64 out)
__global__ __launch_bounds__(256) void k_proj2(const float* __restrict__ h1cat, const float* __restrict__ w2,
                                               const float* __restrict__ as2, const float* __restrict__ ad2,
                                               float* __restrict__ h2p, float* __restrict__ e2s,
                                               float* __restrict__ e2d)
{
    int b = blockIdx.y, chunk = blockIdx.x;
    int t = threadIdx.x, slot = t >> 7, lane = t & 127;
    int fh = lane >> 6, o = lane & 63;
    float wreg[64];
#pragma unroll
    for (int j = 0; j < 64; ++j) wreg[j] = w2[(fh * 64 + j) * 64 + o];
    float as_r = as2[o], ad_r = ad2[o];
    __shared__ __align__(16) float xs[2][128];
    __shared__ float part[2][128];
    for (int i = 0; i < 8; ++i) {
        int n = chunk * 16 + i * 2 + slot;
        bool valid = n < NN;
        if (valid) xs[slot][lane] = h1cat[(size_t)(b * NN + n) * 128 + lane];
        __syncthreads();
        float acc = 0.f;
        if (valid) {
#pragma unroll
            for (int j4 = 0; j4 < 16; ++j4) {
                float4 xv = *(const float4*)&xs[slot][fh * 64 + j4 * 4];
                acc += xv.x * wreg[j4 * 4] + xv.y * wreg[j4 * 4 + 1]
                     + xv.z * wreg[j4 * 4 + 2] + xv.w * wreg[j4 * 4 + 3];
            }
        }
        part[slot][lane] = acc;
        __syncthreads();
        if (valid && fh == 0) {
            float val = acc + part[slot][64 + o];
            h2p[(size_t)(b * NN + n) * 64 + o] = val;
            float vs = val * as_r, vd = val * ad_r;
#pragma unroll
            for (int m = 1; m < 64; m <<= 1) { vs += __shfl_xor(vs, m); vd += __shfl_xor(vd, m); }
            if (o == 0) { e2s[b * NN + n] = vs; e2d[b * NN + n] = vd; }
        }
        __syncthreads();
    }
}

// ---------------- K4: layer-2 sparse attention aggregate + valid mask -> xc ----------------
__global__ __launch_bounds__(64) void k_agg2(const int* __restrict__ nbr, const int* __restrict__ cnt,
                                             const float* __restrict__ h2p, const float* __restrict__ e2s,
                                             const float* __restrict__ e2d, float* __restrict__ xc)
{
    int row = blockIdx.x;
    int b = row / NN, n = row - b * NN;
    int t = threadIdx.x;
    if (n >= NVALID) { xc[(size_t)row * 64 + t] = 0.f; return; }   // padded rows must be exactly 0
    __shared__ int nb_s[MAXK];
    __shared__ float p_s[MAXK];
    __shared__ float stat[2];
    int K = cnt[row];
    for (int k = t; k < K; k += 64) nb_s[k] = nbr[(size_t)row * MAXK + k];
    __syncthreads();
    float es = e2s[row];
    for (int k = t; k < K; k += 64) {
        float e = es + e2d[b * NN + nb_s[k]];
        p_s[k] = e > 0.f ? e : 0.2f * e;
    }
    __syncthreads();
    if (t == 0) {
        float mx = -1e30f;
        for (int k = 0; k < K; ++k) mx = fmaxf(mx, p_s[k]);
        float sum = 0.f;
        for (int k = 0; k < K; ++k) sum += __expf(p_s[k] - mx);
        stat[0] = mx; stat[1] = 1.f / sum;
    }
    __syncthreads();
    for (int k = t; k < K; k += 64) p_s[k] = __expf(p_s[k] - stat[0]) * stat[1];
    __syncthreads();
    float acc = 0.f;
    for (int k = 0; k < K; ++k) acc += p_s[k] * h2p[(size_t)(b * NN + nb_s[k]) * 64 + t];
    xc[(size_t)row * 64 + t] = acc;
}

// ---------------- K5: post-attn pooling (one block per batch) ----------------
__global__ __launch_bounds__(256) void k_pool(const float* __restrict__ xc, const float* __restrict__ aw,
                                              float* __restrict__ out)
{
    int b = blockIdx.x;
    int t = threadIdx.x, w = t >> 6, lane = t & 63;
    __shared__ float score_s[NN];
    __shared__ float red[8];
    __shared__ float part[4][64];
    __shared__ float rd_s;
    const float* xb = xc + (size_t)b * NN * 64;
    if (w == 0) {                       // root-feature dot with aw[64:128]
        float v = xb[lane] * aw[64 + lane];
#pragma unroll
        for (int m = 1; m < 64; m <<= 1) v += __shfl_xor(v, m);
        if (lane == 0) rd_s = v;
    }
    __syncthreads();
    float root_dot = rd_s;
    for (int n = w; n < NN; n += 4) {
        float v = xb[(size_t)n * 64 + lane] * aw[lane];
#pragma unroll
        for (int m = 1; m < 64; m <<= 1) v += __shfl_xor(v, m);
        if (lane == 0) {
            float s = v + (n < NVALID ? root_dot : 0.f);
            if (s == 0.f) s = NEG_INF;  // masked_fill(score==0)
            score_s[n] = s;
        }
    }
    __syncthreads();
    float mx = -1e30f;
    for (int n = t; n < NN; n += 256) mx = fmaxf(mx, score_s[n]);
#pragma unroll
    for (int m = 1; m < 64; m <<= 1) mx = fmaxf(mx, __shfl_xor(mx, m));
    if (lane == 0) red[w] = mx;
    __syncthreads();
    mx = fmaxf(fmaxf(red[0], red[1]), fmaxf(red[2], red[3]));
    float sum = 0.f;
    for (int n = t; n < NN; n += 256) sum += __expf(score_s[n] - mx);
#pragma unroll
    for (int m = 1; m < 64; m <<= 1) sum += __shfl_xor(sum, m);
    if (lane == 0) red[4 + w] = sum;
    __syncthreads();
    float inv = 1.f / (red[4] + red[5] + red[6] + red[7]);
    for (int n = t; n < NN; n += 256) {
        float a = __expf(score_s[n] - mx) * inv;
        out[NB * 64 + b * NN + n] = a;      // attn output
        score_s[n] = a;                     // own slot: no race
    }
    __syncthreads();
    float acc = 0.f;
    for (int n = w; n < NN; n += 4) acc += score_s[n] * xb[(size_t)n * 64 + lane];
    part[w][lane] = acc;
    __syncthreads();
    if (t < 64) out[b * 64 + t] = part[0][t] + part[1][t] + part[2][t] + part[3][t];
}

extern "C" void kernel_launch(void* const* d_in, const int* in_sizes, int n_in,
                              void* d_out, int out_size, void* d_ws, size_t ws_size,
                              hipStream_t stream) {
    const float* x   = (const float*)d_in[0];
    const float* A   = (const float*)d_in[1];
    const float* w1  = (const float*)d_in[4];
    const float* as1 = (const float*)d_in[5];
    const float* ad1 = (const float*)d_in[6];
    const float* w2  = (const float*)d_in[7];
    const float* as2 = (const float*)d_in[8];
    const float* ad2 = (const float*)d_in[9];
    const float* aw  = (const float*)d_in[10];
    float* out = (float*)d_out;

    char* ws = (char*)d_ws;
    int* nbr = (int*)ws;                               // [16000][128]
    int* cnt = (int*)(ws + (size_t)16000 * 128 * 4);   // [16000]
    float* f = (float*)(ws + (size_t)16000 * 129 * 4);
    float* h1p   = f;  f += (size_t)NB * NHEAD * NN * HHID;  // [32][8][500][16]
    float* e1s   = f;  f += (size_t)NB * NHEAD * NN;
    float* e1d   = f;  f += (size_t)NB * NHEAD * NN;
    float* h1cat = f;  f += (size_t)NB * NN * 128;
    float* h2p   = f;  f += (size_t)NB * NN * 64;
    float* e2s   = f;  f += (size_t)NB * NN;
    float* e2d   = f;  f += (size_t)NB * NN;
    float* xc    = f;  f += (size_t)NB * NN * 64;

    hipLaunchKernelGGL(k_nbr,   dim3(4000),   dim3(256), 0, stream, A, nbr, cnt);
    hipLaunchKernelGGL(k_proj1, dim3(32, NB), dim3(256), 0, stream, x, w1, as1, ad1, h1p, e1s, e1d);
    hipLaunchKernelGGL(k_agg1,  dim3(NB * NN), dim3(128), 0, stream, nbr, cnt, h1p, e1s, e1d, h1cat);
    hipLaunchKernelGGL(k_proj2, dim3(32, NB), dim3(256), 0, stream, h1cat, w2, as2, ad2, h2p, e2s, e2d);
    hipLaunchKernelGGL(k_agg2,  dim3(NB * NN), dim3(64), 0, stream, nbr, cnt, h2p, e2s, e2d, xc);
    hipLaunchKernelGGL(k_pool,  dim3(NB),     dim3(256), 0, stream, xc, aw, out);
}

// Round 3
// 186.247 us; speedup vs baseline: 1.3365x; 1.3365x over previous
//
#include <hip/hip_runtime.h>

#define NB 32
#define NN 500
#define HIN 64
#define HHID 16
#define NHEAD 8
#define NVALID 400
#define MAXK 128
#define NEG_INF -1e20f

// ---------------- K0: neighbor list build (wave per row, ballot compaction) ----------------
__global__ __launch_bounds__(256) void k_nbr(const float* __restrict__ A,
                                             int* __restrict__ nbr, int* __restrict__ cnt)
{
    int row = blockIdx.x * 4 + (threadIdx.x >> 6);   // b*NN + n
    int lane = threadIdx.x & 63;
    if (row >= NB * NN) return;
    const float* arow = A + (size_t)row * NN;
    int c = 0;
    for (int it = 0; it < 8; ++it) {
        int m = it * 64 + lane;
        bool v = (m < NN) && (arow[m] > 0.0f);
        unsigned long long bal = __ballot(v);
        if (v) {
            int pos = c + __popcll(bal & ((1ull << lane) - 1ull));
            if (pos < MAXK) nbr[(size_t)row * MAXK + pos] = m;
        }
        c += (int)__popcll(bal);
    }
    if (lane == 0) cnt[row] = c < MAXK ? c : MAXK;
}

// ---------------- K1: layer-1 projection + e_src1/e_dst1 ----------------
__global__ __launch_bounds__(256) void k_proj1(const float* __restrict__ x, const float* __restrict__ w1,
                                               const float* __restrict__ as1, const float* __restrict__ ad1,
                                               float* __restrict__ h1p, float* __restrict__ e1s,
                                               float* __restrict__ e1d)
{
    int b = blockIdx.y, chunk = blockIdx.x;
    int t = threadIdx.x, slot = t >> 7, lane = t & 127;
    int h = lane >> 4, o = lane & 15;
    float wreg[64];
#pragma unroll
    for (int f = 0; f < 64; ++f) wreg[f] = w1[h * 1024 + f * 16 + o];
    float as_r = as1[h * 16 + o], ad_r = ad1[h * 16 + o];
    __shared__ __align__(16) float xs[2][64];
    for (int i = 0; i < 8; ++i) {
        int n = chunk * 16 + i * 2 + slot;
        bool valid = n < NN;
        if (valid && lane < 64) xs[slot][lane] = x[(size_t)(b * NN + n) * HIN + lane];
        __syncthreads();
        if (valid) {
            float acc = 0.f;
#pragma unroll
            for (int f4 = 0; f4 < 16; ++f4) {
                float4 xv = *(const float4*)&xs[slot][f4 * 4];
                acc += xv.x * wreg[f4 * 4] + xv.y * wreg[f4 * 4 + 1]
                     + xv.z * wreg[f4 * 4 + 2] + xv.w * wreg[f4 * 4 + 3];
            }
            h1p[((size_t)(b * NHEAD + h) * NN + n) * HHID + o] = acc;
            float vs = acc * as_r, vd = acc * ad_r;
#pragma unroll
            for (int m = 1; m < 16; m <<= 1) { vs += __shfl_xor(vs, m); vd += __shfl_xor(vd, m); }
            if (o == 0) {
                e1s[(size_t)(b * NHEAD + h) * NN + n] = vs;
                e1d[(size_t)(b * NHEAD + h) * NN + n] = vd;
            }
        }
        __syncthreads();
    }
}

// ---------------- K2: layer-1 sparse attention aggregate + ELU -> h1cat ----------------
__global__ __launch_bounds__(128) void k_agg1(const int* __restrict__ nbr, const int* __restrict__ cnt,
                                              const float* __restrict__ h1p, const float* __restrict__ e1s,
                                              const float* __restrict__ e1d, float* __restrict__ h1cat)
{
    int row = blockIdx.x;           // b*NN + n
    int b = row / NN, n = row - b * NN;
    int t = threadIdx.x;
    __shared__ int nb_s[MAXK];
    __shared__ float p_s[NHEAD][MAXK];
    __shared__ float stat[NHEAD][2];
    int K = cnt[row];
    for (int k = t; k < K; k += 128) nb_s[k] = nbr[(size_t)row * MAXK + k];
    __syncthreads();
    for (int idx = t; idx < NHEAD * K; idx += 128) {
        int h = idx / K, k = idx - h * K;
        float e = e1s[(size_t)(b * NHEAD + h) * NN + n]
                + e1d[(size_t)(b * NHEAD + h) * NN + nb_s[k]];
        p_s[h][k] = e > 0.f ? e : 0.2f * e;
    }
    __syncthreads();
    if (t < NHEAD) {
        float mx = -1e30f;
        for (int k = 0; k < K; ++k) mx = fmaxf(mx, p_s[t][k]);
        float sum = 0.f;
        for (int k = 0; k < K; ++k) sum += __expf(p_s[t][k] - mx);
        stat[t][0] = mx; stat[t][1] = 1.f / sum;
    }
    __syncthreads();
    for (int idx = t; idx < NHEAD * K; idx += 128) {
        int h = idx / K, k = idx - h * K;
        p_s[h][k] = __expf(p_s[h][k] - stat[h][0]) * stat[h][1];
    }
    __syncthreads();
    int h = t >> 4, o = t & 15;
    float acc = 0.f;
    const float* hp = h1p + (size_t)(b * NHEAD + h) * NN * HHID + o;
    for (int k = 0; k < K; ++k) acc += p_s[h][k] * hp[(size_t)nb_s[k] * HHID];
    float outv = acc > 0.f ? acc : expm1f(acc);     // ELU
    h1cat[(size_t)row * (NHEAD * HHID) + t] = outv;
}

// ---------------- K3: layer-2 projection + e_src2/e_dst2 ----------------
__global__ __launch_bounds__(256) void k_proj2(const float* __restrict__ h1cat, const float* __restrict__ w2,
                                               const float* __restrict__ as2, const float* __restrict__ ad2,
                                               float* __restrict__ h2p, float* __restrict__ e2s,
                                               float* __restrict__ e2d)
{
    int b = blockIdx.y, chunk = blockIdx.x;
    int t = threadIdx.x, slot = t >> 7, lane = t & 127;
    int fh = lane >> 6, o = lane & 63;
    float wreg[64];
#pragma unroll
    for (int j = 0; j < 64; ++j) wreg[j] = w2[(fh * 64 + j) * 64 + o];
    float as_r = as2[o], ad_r = ad2[o];
    __shared__ __align__(16) float xs[2][128];
    __shared__ float part[2][128];
    for (int i = 0; i < 8; ++i) {
        int n = chunk * 16 + i * 2 + slot;
        bool valid = n < NN;
        if (valid) xs[slot][lane] = h1cat[(size_t)(b * NN + n) * 128 + lane];
        __syncthreads();
        float acc = 0.f;
        if (valid) {
#pragma unroll
            for (int j4 = 0; j4 < 16; ++j4) {
                float4 xv = *(const float4*)&xs[slot][fh * 64 + j4 * 4];
                acc += xv.x * wreg[j4 * 4] + xv.y * wreg[j4 * 4 + 1]
                     + xv.z * wreg[j4 * 4 + 2] + xv.w * wreg[j4 * 4 + 3];
            }
        }
        part[slot][lane] = acc;
        __syncthreads();
        if (valid && fh == 0) {
            float val = acc + part[slot][64 + o];
            h2p[(size_t)(b * NN + n) * 64 + o] = val;
            float vs = val * as_r, vd = val * ad_r;
#pragma unroll
            for (int m = 1; m < 64; m <<= 1) { vs += __shfl_xor(vs, m); vd += __shfl_xor(vd, m); }
            if (o == 0) { e2s[b * NN + n] = vs; e2d[b * NN + n] = vd; }
        }
        __syncthreads();
    }
}

// ---------------- K4: layer-2 sparse aggregate + valid mask -> xc, fused score dots ----------------
__global__ __launch_bounds__(64) void k_agg2(const int* __restrict__ nbr, const int* __restrict__ cnt,
                                             const float* __restrict__ h2p, const float* __restrict__ e2s,
                                             const float* __restrict__ e2d, const float* __restrict__ aw,
                                             float* __restrict__ xc, float* __restrict__ sc,
                                             float* __restrict__ root_dot)
{
    int row = blockIdx.x;
    int b = row / NN, n = row - b * NN;
    int t = threadIdx.x;
    if (n >= NVALID) { xc[(size_t)row * 64 + t] = 0.f; return; }   // padded rows exactly 0
    __shared__ int nb_s[MAXK];
    __shared__ float p_s[MAXK];
    __shared__ float stat[2];
    int K = cnt[row];
    for (int k = t; k < K; k += 64) nb_s[k] = nbr[(size_t)row * MAXK + k];
    __syncthreads();
    float es = e2s[row];
    for (int k = t; k < K; k += 64) {
        float e = es + e2d[b * NN + nb_s[k]];
        p_s[k] = e > 0.f ? e : 0.2f * e;
    }
    __syncthreads();
    if (t == 0) {
        float mx = -1e30f;
        for (int k = 0; k < K; ++k) mx = fmaxf(mx, p_s[k]);
        float sum = 0.f;
        for (int k = 0; k < K; ++k) sum += __expf(p_s[k] - mx);
        stat[0] = mx; stat[1] = 1.f / sum;
    }
    __syncthreads();
    for (int k = t; k < K; k += 64) p_s[k] = __expf(p_s[k] - stat[0]) * stat[1];
    __syncthreads();
    float acc = 0.f;
    for (int k = 0; k < K; ++k) acc += p_s[k] * h2p[(size_t)(b * NN + nb_s[k]) * 64 + t];
    xc[(size_t)row * 64 + t] = acc;
    // fused: score_part[row] = dot(xc_row, aw[0:64])
    float v = acc * aw[t];
#pragma unroll
    for (int m = 1; m < 64; m <<= 1) v += __shfl_xor(v, m);
    if (t == 0) sc[row] = v;
    if (n == 0) {   // root-feature dot with aw[64:128]
        float v2 = acc * aw[64 + t];
#pragma unroll
        for (int m = 1; m < 64; m <<= 1) v2 += __shfl_xor(v2, m);
        if (t == 0) root_dot[b] = v2;
    }
}

// ---------------- K5: softmax over nodes + pooled output (1024 thr, 16 waves) ----------------
__global__ __launch_bounds__(1024) void k_pool(const float* __restrict__ xc, const float* __restrict__ sc,
                                               const float* __restrict__ root_dot, float* __restrict__ out)
{
    int b = blockIdx.x;
    int t = threadIdx.x, w = t >> 6, lane = t & 63;
    __shared__ float attn_s[NN];
    __shared__ float red[16];
    __shared__ float part[16][64];
    const float* xb = xc + (size_t)b * NN * 64;
    float rd = root_dot[b];
    float s = NEG_INF;
    if (t < NVALID) {
        s = sc[b * NN + t] + rd;
        if (s == 0.f) s = NEG_INF;      // masked_fill(score==0); padded rows stay NEG_INF
    }
    float mx = s;
#pragma unroll
    for (int m = 1; m < 64; m <<= 1) mx = fmaxf(mx, __shfl_xor(mx, m));
    if (lane == 0) red[w] = mx;
    __syncthreads();
    mx = red[0];
#pragma unroll
    for (int i = 1; i < 16; ++i) mx = fmaxf(mx, red[i]);
    float e = (t < NN) ? __expf(s - mx) : 0.f;
    float sum = e;
#pragma unroll
    for (int m = 1; m < 64; m <<= 1) sum += __shfl_xor(sum, m);
    __syncthreads();
    if (lane == 0) red[w] = sum;
    __syncthreads();
    sum = 0.f;
#pragma unroll
    for (int i = 0; i < 16; ++i) sum += red[i];
    float inv = 1.f / sum;
    if (t < NN) {
        float a = e * inv;
        out[NB * 64 + b * NN + t] = a;   // attn output
        attn_s[t] = a;
    }
    __syncthreads();
    float acc = 0.f;
    for (int n = w; n < NN; n += 16) acc += attn_s[n] * xb[(size_t)n * 64 + lane];
    part[w][lane] = acc;
    __syncthreads();
    if (t < 64) {
        float v = 0.f;
#pragma unroll
        for (int i = 0; i < 16; ++i) v += part[i][t];
        out[b * 64 + t] = v;
    }
}

extern "C" void kernel_launch(void* const* d_in, const int* in_sizes, int n_in,
                              void* d_out, int out_size, void* d_ws, size_t ws_size,
                              hipStream_t stream) {
    const float* x   = (const float*)d_in[0];
    const float* A   = (const float*)d_in[1];
    const float* w1  = (const float*)d_in[4];
    const float* as1 = (const float*)d_in[5];
    const float* ad1 = (const float*)d_in[6];
    const float* w2  = (const float*)d_in[7];
    const float* as2 = (const float*)d_in[8];
    const float* ad2 = (const float*)d_in[9];
    const float* aw  = (const float*)d_in[10];
    float* out = (float*)d_out;

    char* ws = (char*)d_ws;
    int* nbr = (int*)ws;                               // [16000][128]
    int* cnt = (int*)(ws + (size_t)16000 * 128 * 4);   // [16000]
    float* f = (float*)(ws + (size_t)16000 * 129 * 4);
    float* h1p   = f;  f += (size_t)NB * NHEAD * NN * HHID;  // [32][8][500][16]
    float* e1s   = f;  f += (size_t)NB * NHEAD * NN;
    float* e1d   = f;  f += (size_t)NB * NHEAD * NN;
    float* h1cat = f;  f += (size_t)NB * NN * 128;
    float* h2p   = f;  f += (size_t)NB * NN * 64;
    float* e2s   = f;  f += (size_t)NB * NN;
    float* e2d   = f;  f += (size_t)NB * NN;
    float* xc    = f;  f += (size_t)NB * NN * 64;
    float* sc    = f;  f += (size_t)NB * NN;
    float* rootd = f;  f += NB;

    hipLaunchKernelGGL(k_nbr,   dim3(4000),   dim3(256), 0, stream, A, nbr, cnt);
    hipLaunchKernelGGL(k_proj1, dim3(32, NB), dim3(256), 0, stream, x, w1, as1, ad1, h1p, e1s, e1d);
    hipLaunchKernelGGL(k_agg1,  dim3(NB * NN), dim3(128), 0, stream, nbr, cnt, h1p, e1s, e1d, h1cat);
    hipLaunchKernelGGL(k_proj2, dim3(32, NB), dim3(256), 0, stream, h1cat, w2, as2, ad2, h2p, e2s, e2d);
    hipLaunchKernelGGL(k_agg2,  dim3(NB * NN), dim3(64), 0, stream, nbr, cnt, h2p, e2s, e2d, aw, xc, sc, rootd);
    hipLaunchKernelGGL(k_pool,  dim3(NB),     dim3(1024), 0, stream, xc, sc, rootd, out);
}